// Round 1
// baseline (3501.149 us; speedup 1.0000x reference)
//
#include <hip/hip_runtime.h>
#include <math.h>

// CharacterBertCharacterCNN — Round 1: correct fp32 baseline.
// Pipeline: conv+maxpool+relu -> t0 ; highway(t0->t1) ; highway(t1->t0) ; proj(t0->out)
// ws layout: t0 [4096*2048] f32 @ 0, t1 [4096*2048] f32 @ 33.5MB (total 67MB)

#define NTOK 4096
#define NCHAR 50
#define EMB 16
#define TF 2048
#define HID 768
#define TPB 32      // tokens per conv block
#define KK 16       // GEMM k-chunk

// ---------------------------------------------------------------- conv ----

template<int W>
__device__ __forceinline__ void load_wreg(const float* __restrict__ wp, float* wreg) {
  // channel weights are 16*W contiguous floats; 16*W % 4 == 0, 16B aligned
#pragma unroll
  for (int x = 0; x < 4 * W; ++x) {
    const float4 v = *(const float4*)(wp + 4 * x);
    wreg[4 * x + 0] = v.x; wreg[4 * x + 1] = v.y;
    wreg[4 * x + 2] = v.z; wreg[4 * x + 3] = v.w;
  }
}

template<int W>
__device__ __forceinline__ float conv_one(const float* wreg,
                                          const float (*emb)[EMB],
                                          float bias) {
  constexpr int LP = NCHAR + 1 - W;  // valid positions
  float acc[LP];
#pragma unroll
  for (int p = 0; p < LP; ++p) acc[p] = 0.0f;
  // r-outer: read each char row once (4 b128 broadcast reads), scatter to acc[r-j]
#pragma unroll
  for (int r = 0; r < NCHAR; ++r) {
    float row[EMB];
#pragma unroll
    for (int q = 0; q < 4; ++q) {
      const float4 v = *(const float4*)&emb[r][q * 4];
      row[q * 4 + 0] = v.x; row[q * 4 + 1] = v.y;
      row[q * 4 + 2] = v.z; row[q * 4 + 3] = v.w;
    }
#pragma unroll
    for (int j = 0; j < W; ++j) {
      const int p = r - j;              // compile-time (r, j unrolled)
      if (p >= 0 && p < LP) {
#pragma unroll
        for (int i = 0; i < EMB; ++i)
          acc[p] = fmaf(row[i], wreg[i * W + j], acc[p]);
      }
    }
  }
  float m = acc[0];
#pragma unroll
  for (int p = 1; p < LP; ++p) m = fmaxf(m, acc[p]);
  return fmaxf(m + bias, 0.0f);       // relu(max_p(conv) + bias)
}

__global__ __launch_bounds__(256) void conv_kernel(
    const int* __restrict__ ids, const float* __restrict__ cemb,
    const float* __restrict__ w0, const float* __restrict__ b0,
    const float* __restrict__ w1, const float* __restrict__ b1,
    const float* __restrict__ w2, const float* __restrict__ b2,
    const float* __restrict__ w3, const float* __restrict__ b3,
    const float* __restrict__ w4, const float* __restrict__ b4,
    const float* __restrict__ w5, const float* __restrict__ b5,
    const float* __restrict__ w6, const float* __restrict__ b6,
    float* __restrict__ tout) {
  __shared__ float emb_s[NCHAR][EMB];
  const int tid = threadIdx.x;
  const int c = blockIdx.y * 256 + tid;   // output channel 0..2047

  int W, lc; const float* wb; const float* bb;
  if      (c < 32)   { W = 1; lc = c;        wb = w0; bb = b0; }
  else if (c < 64)   { W = 2; lc = c - 32;   wb = w1; bb = b1; }
  else if (c < 128)  { W = 3; lc = c - 64;   wb = w2; bb = b2; }
  else if (c < 256)  { W = 4; lc = c - 128;  wb = w3; bb = b3; }
  else if (c < 512)  { W = 5; lc = c - 256;  wb = w4; bb = b4; }
  else if (c < 1024) { W = 6; lc = c - 512;  wb = w5; bb = b5; }
  else               { W = 7; lc = c - 1024; wb = w6; bb = b6; }

  const float* wp = wb + (size_t)lc * EMB * W;
  const float bias = bb[lc];
  float wreg[112];  // weights live in VGPRs for the whole block
  switch (W) {
    case 1: load_wreg<1>(wp, wreg); break;
    case 2: load_wreg<2>(wp, wreg); break;
    case 3: load_wreg<3>(wp, wreg); break;
    case 4: load_wreg<4>(wp, wreg); break;
    case 5: load_wreg<5>(wp, wreg); break;
    case 6: load_wreg<6>(wp, wreg); break;
    default: load_wreg<7>(wp, wreg); break;
  }

  const int tok0 = blockIdx.x * TPB;
  for (int tt = 0; tt < TPB; ++tt) {
    const int tok = tok0 + tt;
    __syncthreads();                      // protect emb_s reuse
    if (tid < 200) {                      // 50 rows x 4 quads
      const int row = tid >> 2, q = tid & 3;
      const int id = ids[tok * NCHAR + row];
      *(float4*)&emb_s[row][q * 4] = *(const float4*)&cemb[id * EMB + q * 4];
    }
    __syncthreads();
    float res;
    switch (W) {
      case 1: res = conv_one<1>(wreg, (const float(*)[EMB])emb_s, bias); break;
      case 2: res = conv_one<2>(wreg, (const float(*)[EMB])emb_s, bias); break;
      case 3: res = conv_one<3>(wreg, (const float(*)[EMB])emb_s, bias); break;
      case 4: res = conv_one<4>(wreg, (const float(*)[EMB])emb_s, bias); break;
      case 5: res = conv_one<5>(wreg, (const float(*)[EMB])emb_s, bias); break;
      case 6: res = conv_one<6>(wreg, (const float(*)[EMB])emb_s, bias); break;
      default: res = conv_one<7>(wreg, (const float(*)[EMB])emb_s, bias); break;
    }
    tout[(size_t)tok * TF + c] = res;     // coalesced
  }
}

// ------------------------------------------------------------- highway ----
// t_next = g * t + (1-g) * relu(nl);  nl = t@W[:, n], gate = t@W[:, 2048+n]
// 128x128 tile, 256 threads, 8x8 per thread, fused dual-B + gating epilogue.

__global__ __launch_bounds__(256) void highway_kernel(
    const float* __restrict__ tin, const float* __restrict__ Wm,
    const float* __restrict__ bv, float* __restrict__ tout) {
  __shared__ float As[KK][128];
  __shared__ float Bns[KK][128];
  __shared__ float Bgs[KK][128];
  const int tid = threadIdx.x;
  const int tx = tid & 15, ty = tid >> 4;
  const int m0 = blockIdx.y * 128, n0 = blockIdx.x * 128;

  float accn[8][8], accg[8][8];
#pragma unroll
  for (int r = 0; r < 8; ++r)
#pragma unroll
    for (int cc = 0; cc < 8; ++cc) { accn[r][cc] = 0.0f; accg[r][cc] = 0.0f; }

  for (int k0 = 0; k0 < TF; k0 += KK) {
#pragma unroll
    for (int u = 0; u < 2; ++u) {
      const int q = tid * 2 + u;          // 0..511
      // A: 128 rows x 16 k, transposed store
      const int row = q >> 2, seg = q & 3;
      const float4 va = *(const float4*)&tin[(size_t)(m0 + row) * TF + k0 + seg * 4];
      As[seg * 4 + 0][row] = va.x; As[seg * 4 + 1][row] = va.y;
      As[seg * 4 + 2][row] = va.z; As[seg * 4 + 3][row] = va.w;
      // B: 16 k-rows x 128 cols, two tiles (nl, gate)
      const int kr = q >> 5, cs = q & 31;
      *(float4*)&Bns[kr][cs * 4] =
          *(const float4*)&Wm[(size_t)(k0 + kr) * (2 * TF) + n0 + cs * 4];
      *(float4*)&Bgs[kr][cs * 4] =
          *(const float4*)&Wm[(size_t)(k0 + kr) * (2 * TF) + TF + n0 + cs * 4];
    }
    __syncthreads();
#pragma unroll
    for (int kk = 0; kk < KK; ++kk) {
      float a[8], bn[8], bg[8];
      *(float4*)&a[0]  = *(const float4*)&As[kk][ty * 8];
      *(float4*)&a[4]  = *(const float4*)&As[kk][ty * 8 + 4];
      *(float4*)&bn[0] = *(const float4*)&Bns[kk][tx * 8];
      *(float4*)&bn[4] = *(const float4*)&Bns[kk][tx * 8 + 4];
      *(float4*)&bg[0] = *(const float4*)&Bgs[kk][tx * 8];
      *(float4*)&bg[4] = *(const float4*)&Bgs[kk][tx * 8 + 4];
#pragma unroll
      for (int r = 0; r < 8; ++r)
#pragma unroll
        for (int cc = 0; cc < 8; ++cc) {
          accn[r][cc] = fmaf(a[r], bn[cc], accn[r][cc]);
          accg[r][cc] = fmaf(a[r], bg[cc], accg[r][cc]);
        }
    }
    __syncthreads();
  }

  float bnl[8], bgt[8];
  *(float4*)&bnl[0] = *(const float4*)&bv[n0 + tx * 8];
  *(float4*)&bnl[4] = *(const float4*)&bv[n0 + tx * 8 + 4];
  *(float4*)&bgt[0] = *(const float4*)&bv[TF + n0 + tx * 8];
  *(float4*)&bgt[4] = *(const float4*)&bv[TF + n0 + tx * 8 + 4];
#pragma unroll
  for (int r = 0; r < 8; ++r) {
    const int m = m0 + ty * 8 + r;
    float told[8], o[8];
    *(float4*)&told[0] = *(const float4*)&tin[(size_t)m * TF + n0 + tx * 8];
    *(float4*)&told[4] = *(const float4*)&tin[(size_t)m * TF + n0 + tx * 8 + 4];
#pragma unroll
    for (int cc = 0; cc < 8; ++cc) {
      const float nl = accn[r][cc] + bnl[cc];
      const float g = 1.0f / (1.0f + expf(-(accg[r][cc] + bgt[cc])));
      o[cc] = g * told[cc] + (1.0f - g) * fmaxf(nl, 0.0f);
    }
    *(float4*)&tout[(size_t)m * TF + n0 + tx * 8]     = *(float4*)&o[0];
    *(float4*)&tout[(size_t)m * TF + n0 + tx * 8 + 4] = *(float4*)&o[4];
  }
}

// ---------------------------------------------------------------- proj ----

__global__ __launch_bounds__(256) void proj_kernel(
    const float* __restrict__ tin, const float* __restrict__ Wm,
    const float* __restrict__ bv, float* __restrict__ out) {
  __shared__ float As[KK][128];
  __shared__ float Bs[KK][128];
  const int tid = threadIdx.x;
  const int tx = tid & 15, ty = tid >> 4;
  const int m0 = blockIdx.y * 128, n0 = blockIdx.x * 128;

  float acc[8][8];
#pragma unroll
  for (int r = 0; r < 8; ++r)
#pragma unroll
    for (int cc = 0; cc < 8; ++cc) acc[r][cc] = 0.0f;

  for (int k0 = 0; k0 < TF; k0 += KK) {
#pragma unroll
    for (int u = 0; u < 2; ++u) {
      const int q = tid * 2 + u;
      const int row = q >> 2, seg = q & 3;
      const float4 va = *(const float4*)&tin[(size_t)(m0 + row) * TF + k0 + seg * 4];
      As[seg * 4 + 0][row] = va.x; As[seg * 4 + 1][row] = va.y;
      As[seg * 4 + 2][row] = va.z; As[seg * 4 + 3][row] = va.w;
      const int kr = q >> 5, cs = q & 31;
      *(float4*)&Bs[kr][cs * 4] =
          *(const float4*)&Wm[(size_t)(k0 + kr) * HID + n0 + cs * 4];
    }
    __syncthreads();
#pragma unroll
    for (int kk = 0; kk < KK; ++kk) {
      float a[8], b[8];
      *(float4*)&a[0] = *(const float4*)&As[kk][ty * 8];
      *(float4*)&a[4] = *(const float4*)&As[kk][ty * 8 + 4];
      *(float4*)&b[0] = *(const float4*)&Bs[kk][tx * 8];
      *(float4*)&b[4] = *(const float4*)&Bs[kk][tx * 8 + 4];
#pragma unroll
      for (int r = 0; r < 8; ++r)
#pragma unroll
        for (int cc = 0; cc < 8; ++cc)
          acc[r][cc] = fmaf(a[r], b[cc], acc[r][cc]);
    }
    __syncthreads();
  }

  float bb[8];
  *(float4*)&bb[0] = *(const float4*)&bv[n0 + tx * 8];
  *(float4*)&bb[4] = *(const float4*)&bv[n0 + tx * 8 + 4];
#pragma unroll
  for (int r = 0; r < 8; ++r) {
    const int m = m0 + ty * 8 + r;
    float o[8];
#pragma unroll
    for (int cc = 0; cc < 8; ++cc) o[cc] = acc[r][cc] + bb[cc];
    *(float4*)&out[(size_t)m * HID + n0 + tx * 8]     = *(float4*)&o[0];
    *(float4*)&out[(size_t)m * HID + n0 + tx * 8 + 4] = *(float4*)&o[4];
  }
}

// -------------------------------------------------------------- launch ----

extern "C" void kernel_launch(void* const* d_in, const int* in_sizes, int n_in,
                              void* d_out, int out_size, void* d_ws, size_t ws_size,
                              hipStream_t stream) {
  const int*   ids  = (const int*)d_in[0];
  const float* cemb = (const float*)d_in[1];
  const float* cw[7]; const float* cb[7];
  for (int i = 0; i < 7; ++i) {
    cw[i] = (const float*)d_in[2 + 2 * i];
    cb[i] = (const float*)d_in[3 + 2 * i];
  }
  const float* hw_w0  = (const float*)d_in[16];
  const float* hw_b0  = (const float*)d_in[17];
  const float* hw_w1  = (const float*)d_in[18];
  const float* hw_b1  = (const float*)d_in[19];
  const float* proj_w = (const float*)d_in[20];
  const float* proj_b = (const float*)d_in[21];
  float* out = (float*)d_out;

  float* t0 = (float*)d_ws;
  float* t1 = t0 + (size_t)NTOK * TF;

  conv_kernel<<<dim3(NTOK / TPB, 8), 256, 0, stream>>>(
      ids, cemb, cw[0], cb[0], cw[1], cb[1], cw[2], cb[2], cw[3], cb[3],
      cw[4], cb[4], cw[5], cb[5], cw[6], cb[6], t0);

  highway_kernel<<<dim3(TF / 128, NTOK / 128), 256, 0, stream>>>(t0, hw_w0, hw_b0, t1);
  highway_kernel<<<dim3(TF / 128, NTOK / 128), 256, 0, stream>>>(t1, hw_w1, hw_b1, t0);
  proj_kernel<<<dim3(HID / 128, NTOK / 128), 256, 0, stream>>>(t0, proj_w, proj_b, out);
}